// Round 9
// baseline (33.544 us; speedup 1.0000x reference)
//
#include <hip/hip_runtime.h>
#include <math.h>
#include <stdint.h>

#define HH 128
#define WW 128
#define NFLOATS (16 * 64 * HH * WW)   // 16,777,216

typedef __fp16 h2 __attribute__((ext_vector_type(2)));

__device__ __forceinline__ h2 h2max(h2 a, h2 b) { return __builtin_elementwise_max(a, b); }
__device__ __forceinline__ uint32_t h2u(h2 v) { return __builtin_bit_cast(uint32_t, v); }
__device__ __forceinline__ h2 uh2(uint32_t v) { return __builtin_bit_cast(h2, v); }

#if __has_builtin(__builtin_elementwise_fma)
#define H2FMA(a, b, c) __builtin_elementwise_fma((a), (b), (c))
#else
#define H2FMA(a, b, c) ((a) * (b) + (c))   // -ffp-contract folds to v_pk_fma_f16
#endif

__global__ __launch_bounds__(256, 8) void morpho_kernel(
    const float* __restrict__ x,     // [B,C,128,128]
    const float* __restrict__ wgt,   // [B,C,5,5]
    const float* __restrict__ bias,  // [B,C]
    const float* __restrict__ sign,  // [B]
    float* __restrict__ out)         // [B,C,128,128]
{
    // T1: XCD-contiguous block chunks (4096 % 8 == 0 -> bijective)
    const int bid  = blockIdx.x;
    const int blk  = (bid & 7) * 512 + (bid >> 3);
    const int quad = blk & 3;        // 32-row band
    const int bc   = blk >> 2;       // plane = b*64 + c
    const int b    = bc >> 6;

    float*       __restrict__ yp = out + (size_t)bc * (HH * WW);
    const float* __restrict__ wp = wgt + bc * 25;

    const float sgn = sign[b];
    const float s   = (fabsf(sgn) >= 1e-7f) ? sgn : 1.0f;
    const float bvs = bias[bc] * s;
    const __fp16 sh = (__fp16)s;
    const h2 s2 = { sh, sh };

    // weights as broadcast f16 pairs -> SGPRs (block-uniform)
    uint32_t wsu[25];
#pragma unroll
    for (int k = 0; k < 25; ++k) {
        const __fp16 wh = (__fp16)wp[k];
        h2 w2 = { wh, wh };
        wsu[k] = (uint32_t)__builtin_amdgcn_readfirstlane((int)h2u(w2));
    }

    const int t  = threadIdx.x;
    const int tx = t & 31;           // 4-col block
    const int ty = t >> 5;           // 0..7
    const int j0 = tx * 4;
    const int i0 = quad * 32 + ty * 4;
    const int planeOff = bc * (HH * WW);

    const bool mL = (tx > 0);        // cols j0-2,j0-1 exist
    const bool mR = (tx < 31);       // cols j0+4,j0+5 exist

    h2 acc0[4], acc1[4];             // out col pairs (j0,j0+1), (j0+2,j0+3)

#pragma unroll
    for (int r8 = 0; r8 < 8; ++r8) {
        const int  r  = i0 - 2 + r8;
        const bool rv = ((unsigned)r < (unsigned)HH);
        const int  rc = min(max(r, 0), HH - 1);
        const int  oM = planeOff + rc * WW + j0;
        const int  oL = max(oM - 4, 0);
        const int  oR = min(oM + 4, NFLOATS - 4);
        const float4 v0 = *reinterpret_cast<const float4*>(x + oL);
        const float4 v1 = *reinterpret_cast<const float4*>(x + oM);
        const float4 v2 = *reinterpret_cast<const float4*>(x + oR);

        // even col-pairs rel j0: e0=(-2,-1) e1=(0,1) e2=(2,3) e3=(4,5)
        uint32_t e0 = h2u(__builtin_amdgcn_cvt_pkrtz(v0.z, v0.w));
        uint32_t e1 = h2u(__builtin_amdgcn_cvt_pkrtz(v1.x, v1.y));
        uint32_t e2 = h2u(__builtin_amdgcn_cvt_pkrtz(v1.z, v1.w));
        uint32_t e3 = h2u(__builtin_amdgcn_cvt_pkrtz(v2.x, v2.y));
        // zero pads (row/col) -> tap fma(0,s,w) = w, matching zero-padded ref
        e0 = (rv && mL) ? e0 : 0u;
        e1 = rv ? e1 : 0u;
        e2 = rv ? e2 : 0u;
        e3 = (rv && mR) ? e3 : 0u;
        // odd col-pairs via 16-bit funnel shift
        const uint32_t o0 = __builtin_amdgcn_alignbit(e1, e0, 16);  // (-1,0)
        const uint32_t o1 = __builtin_amdgcn_alignbit(e2, e1, 16);  // (1,2)
        const uint32_t o2 = __builtin_amdgcn_alignbit(e3, e2, 16);  // (3,4)

        const uint32_t P0[5] = { e0, o0, e1, o1, e2 };  // pair0 taps q=0..4
        const uint32_t P1[5] = { e1, o1, e2, o2, e3 };  // pair1 taps q=0..4

#pragma unroll
        for (int p = 0; p < 5; ++p) {
            const int oi = r8 - p;   // output row fed by this input row
            if (oi >= 0 && oi < 4) {
                const h2 w0 = uh2(wsu[p * 5 + 0]);
                const h2 w1 = uh2(wsu[p * 5 + 1]);
                const h2 w2 = uh2(wsu[p * 5 + 2]);
                const h2 w3 = uh2(wsu[p * 5 + 3]);
                const h2 w4 = uh2(wsu[p * 5 + 4]);
                {
                    const h2 t0 = H2FMA(uh2(P0[0]), s2, w0);
                    const h2 t1 = H2FMA(uh2(P0[1]), s2, w1);
                    const h2 t2 = H2FMA(uh2(P0[2]), s2, w2);
                    const h2 t3 = H2FMA(uh2(P0[3]), s2, w3);
                    const h2 t4 = H2FMA(uh2(P0[4]), s2, w4);
                    h2 mm = h2max(h2max(h2max(t0, t1), h2max(t2, t3)), t4);
                    acc0[oi] = (p == 0) ? mm : h2max(acc0[oi], mm);
                }
                {
                    const h2 t0 = H2FMA(uh2(P1[0]), s2, w0);
                    const h2 t1 = H2FMA(uh2(P1[1]), s2, w1);
                    const h2 t2 = H2FMA(uh2(P1[2]), s2, w2);
                    const h2 t3 = H2FMA(uh2(P1[3]), s2, w3);
                    const h2 t4 = H2FMA(uh2(P1[4]), s2, w4);
                    h2 mm = h2max(h2max(h2max(t0, t1), h2max(t2, t3)), t4);
                    acc1[oi] = (p == 0) ? mm : h2max(acc1[oi], mm);
                }
            }
        }
    }

    // epilogue: y = acc*s + bias*s in f32
#pragma unroll
    for (int a = 0; a < 4; ++a) {
        float4 o;
        o.x = fmaf((float)acc0[a][0], s, bvs);
        o.y = fmaf((float)acc0[a][1], s, bvs);
        o.z = fmaf((float)acc1[a][0], s, bvs);
        o.w = fmaf((float)acc1[a][1], s, bvs);
        *reinterpret_cast<float4*>(yp + (size_t)(i0 + a) * WW + j0) = o;
    }
}

extern "C" void kernel_launch(void* const* d_in, const int* in_sizes, int n_in,
                              void* d_out, int out_size, void* d_ws, size_t ws_size,
                              hipStream_t stream) {
    (void)d_ws; (void)ws_size; (void)in_sizes; (void)n_in; (void)out_size;
    const float* x    = (const float*)d_in[0];
    const float* w    = (const float*)d_in[1];
    const float* bias = (const float*)d_in[2];
    const float* sign = (const float*)d_in[3];
    float* out = (float*)d_out;

    morpho_kernel<<<4096, 256, 0, stream>>>(x, w, bias, sign, out);
}

// Round 10
// 33.253 us; speedup vs baseline: 1.0087x; 1.0087x over previous
//
#include <hip/hip_runtime.h>
#include <math.h>
#include <stdint.h>

#define HH 128
#define WW 128
#define ROWU 72              // u32 per LDS row = 144 f16: cols -8..135 (8-halo each side)
#define LROWS 36
#define UNITS 648            // 36 rows * 18 16B-units
#define LDSU (LROWS * ROWU)  // 2592 u32 = 10368 B per buffer

typedef __fp16 h2 __attribute__((ext_vector_type(2)));

__device__ __forceinline__ h2 h2max(h2 a, h2 b) { return __builtin_elementwise_max(a, b); }
__device__ __forceinline__ uint32_t h2u(h2 v) { return __builtin_bit_cast(uint32_t, v); }
__device__ __forceinline__ h2 uh2(uint32_t v) { return __builtin_bit_cast(h2, v); }

__global__ __launch_bounds__(256, 6) void morpho_kernel(
    const float* __restrict__ x,     // [B,C,128,128]
    const float* __restrict__ wgt,   // [B,C,5,5]
    const float* __restrict__ bias,  // [B,C]
    const float* __restrict__ sign,  // [B]
    float* __restrict__ out)         // [B,C,128,128]
{
    __shared__ uint32_t lds[2][LDSU];

    // T1: XCD-contiguous chunks (2048 % 8 == 0 -> bijective)
    const int bid  = blockIdx.x;
    const int blk  = (bid & 7) * 256 + (bid >> 3);
    const int half = blk & 1;        // 64-row half-plane
    const int bc   = blk >> 1;       // plane = b*64 + c
    const int b    = bc >> 6;

    const float* __restrict__ xp = x   + (size_t)bc * (HH * WW);
    float*       __restrict__ yp = out + (size_t)bc * (HH * WW);
    const float* __restrict__ wp = wgt + bc * 25;

    const float sgn = sign[b];
    const float s   = (fabsf(sgn) >= 1e-7f) ? sgn : 1.0f;
    const float bvs = bias[bc] * s;
    const __fp16 sh = (__fp16)s;
    const h2 s2 = { sh, sh };
    const h2 z2 = { (__fp16)0.f, (__fp16)0.f };

    const int t = threadIdx.x;

    // per-thread staging geometry (tile-invariant): unit u = t + 256k
    int urow[3], uuc[3];
    bool uin[3];
#pragma unroll
    for (int k = 0; k < 3; ++k) {
        const int u = t + k * 256;
        uin[k] = (u < UNITS);
        urow[k] = u / 18;
        uuc[k]  = u - urow[k] * 18;  // 0..17; units 1..16 = cols 0..127, 0/17 = pad
    }

    // ---- issue ALL global loads for both tiles up front ----
    float4 vA0[3], vA1[3], vB0[3], vB1[3];
#pragma unroll
    for (int k = 0; k < 3; ++k) {
        const int cc = min(max(uuc[k] * 8 - 8, 0), WW - 8);
        {
            const int grow = half * 64 - 2 + urow[k];
            const int rc   = min(max(grow, 0), HH - 1);
            const float* gp = xp + rc * WW + cc;
            vA0[k] = *reinterpret_cast<const float4*>(gp);
            vA1[k] = *reinterpret_cast<const float4*>(gp + 4);
        }
        {
            const int grow = half * 64 + 30 + urow[k];
            const int rc   = min(max(grow, 0), HH - 1);
            const float* gp = xp + rc * WW + cc;
            vB0[k] = *reinterpret_cast<const float4*>(gp);
            vB1[k] = *reinterpret_cast<const float4*>(gp + 4);
        }
    }
    asm volatile("" ::: "memory");   // pin load issue above everything below

    // weights as broadcast f16 pairs -> SGPRs (block-uniform)
    uint32_t wsu[25];
#pragma unroll
    for (int k = 0; k < 25; ++k) {
        const __fp16 wh = (__fp16)wp[k];
        h2 w2 = { wh, wh };
        wsu[k] = (uint32_t)__builtin_amdgcn_readfirstlane((int)h2u(w2));
    }

    const int tx = t & 31;
    const int ty = t >> 5;
    const int j0 = tx * 4;

    // ---- cvt + LDS write for one tile (prescale by s, zero pads) ----
    auto CVT_WRITE = [&](int buf, const float4* v0, const float4* v1, int tile) {
#pragma unroll
        for (int k = 0; k < 3; ++k) {
            if (uin[k]) {
                const int grow = half * 64 + tile * 32 - 2 + urow[k];
                const bool valid = (uuc[k] >= 1) && (uuc[k] <= 16) &&
                                   ((unsigned)grow < (unsigned)HH);
                const h2 m = valid ? s2 : z2;
                const h2 h0 = __builtin_amdgcn_cvt_pkrtz(v0[k].x, v0[k].y) * m;
                const h2 h1 = __builtin_amdgcn_cvt_pkrtz(v0[k].z, v0[k].w) * m;
                const h2 hv = __builtin_amdgcn_cvt_pkrtz(v1[k].x, v1[k].y) * m;
                const h2 h3 = __builtin_amdgcn_cvt_pkrtz(v1[k].z, v1[k].w) * m;
                uint4 o;
                o.x = h2u(h0); o.y = h2u(h1); o.z = h2u(hv); o.w = h2u(h3);
                *reinterpret_cast<uint4*>(&lds[buf][urow[k] * ROWU + uuc[k] * 4]) = o;
            }
        }
    };

    // ---- packed-f16 compute for one tile (R8-verified tap layout) ----
    auto COMPUTE = [&](int buf, int tile) {
        h2 acc0[4], acc1[4];
#pragma unroll
        for (int r8 = 0; r8 < 8; ++r8) {
            const uint32_t* lp = &lds[buf][(ty * 4 + r8) * ROWU + 2 * tx + 2];
            const uint32_t r1 = lp[1];
            const uint2  d23 = *reinterpret_cast<const uint2*>(lp + 2);
            const uint32_t r2 = d23.x, r3 = d23.y;
            const uint32_t r4 = lp[4];
            const uint32_t o0 = __builtin_amdgcn_alignbit(r2, r1, 16);
            const uint32_t o1 = __builtin_amdgcn_alignbit(r3, r2, 16);
            const uint32_t o2 = __builtin_amdgcn_alignbit(r4, r3, 16);
            const uint32_t P0[5] = { r1, o0, r2, o1, r3 };
            const uint32_t P1[5] = { r2, o1, r3, o2, r4 };
#pragma unroll
            for (int p = 0; p < 5; ++p) {
                const int oi = r8 - p;
                if (oi >= 0 && oi < 4) {
                    {
                        const h2 t0 = uh2(P0[0]) + uh2(wsu[p * 5 + 0]);
                        const h2 t1 = uh2(P0[1]) + uh2(wsu[p * 5 + 1]);
                        const h2 t2 = uh2(P0[2]) + uh2(wsu[p * 5 + 2]);
                        const h2 t3 = uh2(P0[3]) + uh2(wsu[p * 5 + 3]);
                        const h2 t4 = uh2(P0[4]) + uh2(wsu[p * 5 + 4]);
                        h2 mm = h2max(h2max(h2max(t0, t1), h2max(t2, t3)), t4);
                        acc0[oi] = (p == 0) ? mm : h2max(acc0[oi], mm);
                    }
                    {
                        const h2 t0 = uh2(P1[0]) + uh2(wsu[p * 5 + 0]);
                        const h2 t1 = uh2(P1[1]) + uh2(wsu[p * 5 + 1]);
                        const h2 t2 = uh2(P1[2]) + uh2(wsu[p * 5 + 2]);
                        const h2 t3 = uh2(P1[3]) + uh2(wsu[p * 5 + 3]);
                        const h2 t4 = uh2(P1[4]) + uh2(wsu[p * 5 + 4]);
                        h2 mm = h2max(h2max(h2max(t0, t1), h2max(t2, t3)), t4);
                        acc1[oi] = (p == 0) ? mm : h2max(acc1[oi], mm);
                    }
                }
            }
        }
        const int i0 = half * 64 + tile * 32 + ty * 4;
#pragma unroll
        for (int a = 0; a < 4; ++a) {
            float4 o;
            o.x = fmaf((float)acc0[a][0], s, bvs);
            o.y = fmaf((float)acc0[a][1], s, bvs);
            o.z = fmaf((float)acc1[a][0], s, bvs);
            o.w = fmaf((float)acc1[a][1], s, bvs);
            *reinterpret_cast<float4*>(yp + (size_t)(i0 + a) * WW + j0) = o;
        }
    };

    // ---- 2-tile pipeline: compute(0) runs while nothing blocks; tile1 data
    //      already in regs (loads issued at top) ----
    CVT_WRITE(0, vA0, vA1, 0);       // compiler inserts vmcnt for vA only
    __syncthreads();
    COMPUTE(0, 0);
    CVT_WRITE(1, vB0, vB1, 1);
    __syncthreads();
    COMPUTE(1, 1);
}

extern "C" void kernel_launch(void* const* d_in, const int* in_sizes, int n_in,
                              void* d_out, int out_size, void* d_ws, size_t ws_size,
                              hipStream_t stream) {
    (void)d_ws; (void)ws_size; (void)in_sizes; (void)n_in; (void)out_size;
    const float* x    = (const float*)d_in[0];
    const float* w    = (const float*)d_in[1];
    const float* bias = (const float*)d_in[2];
    const float* sign = (const float*)d_in[3];
    float* out = (float*)d_out;

    morpho_kernel<<<2048, 256, 0, stream>>>(x, w, bias, sign, out);
}

// Round 11
// 29.920 us; speedup vs baseline: 1.1211x; 1.1114x over previous
//
#include <hip/hip_runtime.h>
#include <math.h>
#include <stdint.h>

#define HH 128
#define WW 128
#define NFLOATS (16 * 64 * HH * WW)   // 16,777,216

typedef __fp16 h2 __attribute__((ext_vector_type(2)));

__device__ __forceinline__ h2 h2max(h2 a, h2 b) { return __builtin_elementwise_max(a, b); }
__device__ __forceinline__ uint32_t h2u(h2 v) { return __builtin_bit_cast(uint32_t, v); }
__device__ __forceinline__ h2 uh2(uint32_t v) { return __builtin_bit_cast(h2, v); }

#if __has_builtin(__builtin_elementwise_fma)
#define H2FMA(a, b, c) __builtin_elementwise_fma((a), (b), (c))
#else
#define H2FMA(a, b, c) ((a) * (b) + (c))   // contracts to v_pk_fma_f16
#endif

// counted wait + scheduling fence (rule #18: consumers must not hoist above)
#define WAITV(n) do { asm volatile("s_waitcnt vmcnt(" #n ")" ::: "memory"); \
                      __builtin_amdgcn_sched_barrier(0); } while (0)

__global__ __launch_bounds__(256) void morpho_kernel(
    const float* __restrict__ x,     // [B,C,128,128]
    const float* __restrict__ wgt,   // [B,C,5,5]
    const float* __restrict__ bias,  // [B,C]
    const float* __restrict__ sign,  // [B]
    float* __restrict__ out)         // [B,C,128,128]
{
    // T1: XCD-contiguous chunks (4096 % 8 == 0 -> bijective)
    const int bid  = blockIdx.x;
    const int blk  = (bid & 7) * 512 + (bid >> 3);
    const int quad = blk & 3;        // 32-row band
    const int bc   = blk >> 2;       // plane = b*64 + c
    const int b    = bc >> 6;

    float*       __restrict__ yp = out + (size_t)bc * (HH * WW);
    const float* __restrict__ wp = wgt + bc * 25;

    const float sgn = sign[b];
    const float s   = (fabsf(sgn) >= 1e-7f) ? sgn : 1.0f;
    const float bvs = bias[bc] * s;
    const __fp16 sh = (__fp16)s;
    const h2 s2 = { sh, sh };

    // weights as broadcast f16 pairs -> SGPRs (block-uniform)
    uint32_t wsu[25];
#pragma unroll
    for (int k = 0; k < 25; ++k) {
        const __fp16 wh = (__fp16)wp[k];
        h2 w2 = { wh, wh };
        wsu[k] = (uint32_t)__builtin_amdgcn_readfirstlane((int)h2u(w2));
    }

    const int t  = threadIdx.x;
    const int tx = t & 31;           // 4-col block
    const int ty = t >> 5;           // 0..7
    const int j0 = tx * 4;
    const int i0 = quad * 32 + ty * 4;
    const int planeOff = bc * (HH * WW);
    const bool mL = (tx > 0);
    const bool mR = (tx < 31);

    float2 vl[8]; float4 vm[8]; float2 vr[8];   // all indices compile-time (unrolled)
    h2 acc0[4], acc1[4];

    // 3 forced in-flight loads per row: cols (j0-2,j0-1), (j0..j0+3), (j0+4,j0+5)
    auto ISSUE = [&](int r8) {
        const int rrow = i0 - 2 + r8;
        const int rc = min(max(rrow, 0), HH - 1);   // v_med3; content masked later
        const int oM = planeOff + rc * WW + j0;
        const int oL = max(oM - 2, 0);
        const int oR = min(oM + 4, NFLOATS - 2);
        asm volatile("global_load_dwordx2 %0, %1, off" : "=v"(vl[r8]) : "v"(x + oL));
        asm volatile("global_load_dwordx4 %0, %1, off" : "=v"(vm[r8]) : "v"(x + oM));
        asm volatile("global_load_dwordx2 %0, %1, off" : "=v"(vr[r8]) : "v"(x + oR));
    };

    auto CONSUME = [&](int r8) {
        const int  rrow = i0 - 2 + r8;
        const bool rv = ((unsigned)rrow < (unsigned)HH);
        // even col-pairs rel j0: e0=(-2,-1) e1=(0,1) e2=(2,3) e3=(4,5)
        uint32_t e0 = h2u(__builtin_amdgcn_cvt_pkrtz(vl[r8].x, vl[r8].y));
        uint32_t e1 = h2u(__builtin_amdgcn_cvt_pkrtz(vm[r8].x, vm[r8].y));
        uint32_t e2 = h2u(__builtin_amdgcn_cvt_pkrtz(vm[r8].z, vm[r8].w));
        uint32_t e3 = h2u(__builtin_amdgcn_cvt_pkrtz(vr[r8].x, vr[r8].y));
        e0 = (rv && mL) ? e0 : 0u;   // zero-pad -> tap fma(0,s,w)=w
        e1 = rv ? e1 : 0u;
        e2 = rv ? e2 : 0u;
        e3 = (rv && mR) ? e3 : 0u;
        const uint32_t o0 = __builtin_amdgcn_alignbit(e1, e0, 16);  // (-1,0)
        const uint32_t o1 = __builtin_amdgcn_alignbit(e2, e1, 16);  // (1,2)
        const uint32_t o2 = __builtin_amdgcn_alignbit(e3, e2, 16);  // (3,4)
        const uint32_t P0[5] = { e0, o0, e1, o1, e2 };
        const uint32_t P1[5] = { e1, o1, e2, o2, e3 };
#pragma unroll
        for (int p = 0; p < 5; ++p) {
            const int oi = r8 - p;
            if (oi >= 0 && oi < 4) {
                const h2 w0 = uh2(wsu[p * 5 + 0]);
                const h2 w1 = uh2(wsu[p * 5 + 1]);
                const h2 w2 = uh2(wsu[p * 5 + 2]);
                const h2 w3 = uh2(wsu[p * 5 + 3]);
                const h2 w4 = uh2(wsu[p * 5 + 4]);
                {
                    const h2 t0 = H2FMA(uh2(P0[0]), s2, w0);
                    const h2 t1 = H2FMA(uh2(P0[1]), s2, w1);
                    const h2 t2 = H2FMA(uh2(P0[2]), s2, w2);
                    const h2 t3 = H2FMA(uh2(P0[3]), s2, w3);
                    const h2 t4 = H2FMA(uh2(P0[4]), s2, w4);
                    h2 mm = h2max(h2max(h2max(t0, t1), h2max(t2, t3)), t4);
                    acc0[oi] = (p == 0) ? mm : h2max(acc0[oi], mm);
                }
                {
                    const h2 t0 = H2FMA(uh2(P1[0]), s2, w0);
                    const h2 t1 = H2FMA(uh2(P1[1]), s2, w1);
                    const h2 t2 = H2FMA(uh2(P1[2]), s2, w2);
                    const h2 t3 = H2FMA(uh2(P1[3]), s2, w3);
                    const h2 t4 = H2FMA(uh2(P1[4]), s2, w4);
                    h2 mm = h2max(h2max(h2max(t0, t1), h2max(t2, t3)), t4);
                    acc1[oi] = (p == 0) ? mm : h2max(acc1[oi], mm);
                }
            }
        }
    };

    // ---- rolling 4-row (12-load) window, compiler-proof ----
    ISSUE(0); ISSUE(1); ISSUE(2); ISSUE(3);
    WAITV(9); CONSUME(0); ISSUE(4);
    WAITV(9); CONSUME(1); ISSUE(5);
    WAITV(9); CONSUME(2); ISSUE(6);
    WAITV(9); CONSUME(3); ISSUE(7);
    WAITV(9); CONSUME(4);
    WAITV(6); CONSUME(5);
    WAITV(3); CONSUME(6);
    WAITV(0); CONSUME(7);

    // ---- epilogue: y = acc*s + bias*s in f32 ----
#pragma unroll
    for (int a = 0; a < 4; ++a) {
        float4 o;
        o.x = fmaf((float)acc0[a][0], s, bvs);
        o.y = fmaf((float)acc0[a][1], s, bvs);
        o.z = fmaf((float)acc1[a][0], s, bvs);
        o.w = fmaf((float)acc1[a][1], s, bvs);
        *reinterpret_cast<float4*>(yp + (size_t)(i0 + a) * WW + j0) = o;
    }
}

extern "C" void kernel_launch(void* const* d_in, const int* in_sizes, int n_in,
                              void* d_out, int out_size, void* d_ws, size_t ws_size,
                              hipStream_t stream) {
    (void)d_ws; (void)ws_size; (void)in_sizes; (void)n_in; (void)out_size;
    const float* x    = (const float*)d_in[0];
    const float* w    = (const float*)d_in[1];
    const float* bias = (const float*)d_in[2];
    const float* sign = (const float*)d_in[3];
    float* out = (float*)d_out;

    morpho_kernel<<<4096, 256, 0, stream>>>(x, w, bias, sign, out);
}

// Round 12
// 27.930 us; speedup vs baseline: 1.2010x; 1.0713x over previous
//
#include <hip/hip_runtime.h>
#include <math.h>
#include <stdint.h>

#define HH 128
#define WW 128

typedef __fp16 h2 __attribute__((ext_vector_type(2)));

__device__ __forceinline__ h2 h2max(h2 a, h2 b) { return __builtin_elementwise_max(a, b); }
__device__ __forceinline__ uint32_t h2u(h2 v) { return __builtin_bit_cast(uint32_t, v); }
__device__ __forceinline__ h2 uh2(uint32_t v) { return __builtin_bit_cast(h2, v); }

#if __has_builtin(__builtin_elementwise_fma)
#define H2FMA(a, b, c) __builtin_elementwise_fma((a), (b), (c))
#else
#define H2FMA(a, b, c) ((a) * (b) + (c))   // contracts to v_pk_fma_f16
#endif

// counted wait + scheduling fence (rule #18)
#define WAITV(n) do { asm volatile("s_waitcnt vmcnt(" #n ")" ::: "memory"); \
                      __builtin_amdgcn_sched_barrier(0); } while (0)

__global__ __launch_bounds__(256) void morpho_kernel(
    const float* __restrict__ x,     // [B,C,128,128]
    const float* __restrict__ wgt,   // [B,C,5,5]
    const float* __restrict__ bias,  // [B,C]
    const float* __restrict__ sign,  // [B]
    float* __restrict__ out)         // [B,C,128,128]
{
    // T1: XCD-contiguous chunks (4096 % 8 == 0 -> bijective)
    const int bid  = blockIdx.x;
    const int blk  = (bid & 7) * 512 + (bid >> 3);
    const int quad = blk & 3;        // 32-row band
    const int bc   = blk >> 2;       // plane = b*64 + c
    const int b    = bc >> 6;

    float*       __restrict__ yp = out + (size_t)bc * (HH * WW);
    const float* __restrict__ wp = wgt + bc * 25;

    const float sgn = sign[b];
    const float s   = (fabsf(sgn) >= 1e-7f) ? sgn : 1.0f;
    const float bvs = bias[bc] * s;
    const __fp16 sh = (__fp16)s;
    const h2 s2 = { sh, sh };

    // weights as broadcast f16 pairs -> SGPRs (block-uniform)
    uint32_t wsu[25];
#pragma unroll
    for (int k = 0; k < 25; ++k) {
        const __fp16 wh = (__fp16)wp[k];
        h2 w2 = { wh, wh };
        wsu[k] = (uint32_t)__builtin_amdgcn_readfirstlane((int)h2u(w2));
    }

    const int t  = threadIdx.x;
    const int tx = t & 31;           // 4-col block: cols j0..j0+3
    const int ty = t >> 5;           // 0..7
    const int j0 = tx * 4;
    const int i0 = quad * 32 + ty * 4;
    const int planeOff = bc * (HH * WW);
    const bool mL = (tx > 0);
    const bool mR = (tx < 31);

    // normalize vmcnt to 0 so the counted waits below are exact
    asm volatile("s_waitcnt vmcnt(0)" ::: "memory");

    // ---- issue ALL 8 row-loads up front (16 B/row/thread, own data only) ----
    float4 vm[8];
#pragma unroll
    for (int r8 = 0; r8 < 8; ++r8) {
        const int rrow = i0 - 2 + r8;
        const int rc   = min(max(rrow, 0), HH - 1);   // v_med3; masked later
        const float* gp = x + planeOff + rc * WW + j0;
        asm volatile("global_load_dwordx4 %0, %1, off" : "=v"(vm[r8]) : "v"(gp));
    }

    h2 acc0[4], acc1[4];

#pragma unroll
    for (int r8 = 0; r8 < 8; ++r8) {
        switch (7 - r8) {            // exact FIFO wait for load r8
            case 7: WAITV(7); break;
            case 6: WAITV(6); break;
            case 5: WAITV(5); break;
            case 4: WAITV(4); break;
            case 3: WAITV(3); break;
            case 2: WAITV(2); break;
            case 1: WAITV(1); break;
            default: WAITV(0); break;
        }
        const int  rrow = i0 - 2 + r8;
        const bool rv = ((unsigned)rrow < (unsigned)HH);
        // own even pairs, row-masked (pads -> 0 -> tap fma(0,s,w) = w)
        uint32_t e1 = h2u(__builtin_amdgcn_cvt_pkrtz(vm[r8].x, vm[r8].y));
        uint32_t e2 = h2u(__builtin_amdgcn_cvt_pkrtz(vm[r8].z, vm[r8].w));
        e1 = rv ? e1 : 0u;
        e2 = rv ? e2 : 0u;
        // halo pairs from lane neighbors (left's e2 / right's e1), col-masked
        uint32_t e0 = (uint32_t)__shfl_up((int)e2, 1, 32);
        uint32_t e3 = (uint32_t)__shfl_down((int)e1, 1, 32);
        e0 = mL ? e0 : 0u;
        e3 = mR ? e3 : 0u;
        // odd pairs via 16-bit funnel shift
        const uint32_t o0 = __builtin_amdgcn_alignbit(e1, e0, 16);  // (-1,0)
        const uint32_t o1 = __builtin_amdgcn_alignbit(e2, e1, 16);  // (1,2)
        const uint32_t o2 = __builtin_amdgcn_alignbit(e3, e2, 16);  // (3,4)
        const uint32_t P0[5] = { e0, o0, e1, o1, e2 };
        const uint32_t P1[5] = { e1, o1, e2, o2, e3 };

#pragma unroll
        for (int p = 0; p < 5; ++p) {
            const int oi = r8 - p;   // output row fed by this input row
            if (oi >= 0 && oi < 4) {
                const h2 w0 = uh2(wsu[p * 5 + 0]);
                const h2 w1 = uh2(wsu[p * 5 + 1]);
                const h2 w2 = uh2(wsu[p * 5 + 2]);
                const h2 w3 = uh2(wsu[p * 5 + 3]);
                const h2 w4 = uh2(wsu[p * 5 + 4]);
                {
                    const h2 t0 = H2FMA(uh2(P0[0]), s2, w0);
                    const h2 t1 = H2FMA(uh2(P0[1]), s2, w1);
                    const h2 t2 = H2FMA(uh2(P0[2]), s2, w2);
                    const h2 t3 = H2FMA(uh2(P0[3]), s2, w3);
                    const h2 t4 = H2FMA(uh2(P0[4]), s2, w4);
                    h2 mm = h2max(h2max(h2max(t0, t1), h2max(t2, t3)), t4);
                    acc0[oi] = (p == 0) ? mm : h2max(acc0[oi], mm);
                }
                {
                    const h2 t0 = H2FMA(uh2(P1[0]), s2, w0);
                    const h2 t1 = H2FMA(uh2(P1[1]), s2, w1);
                    const h2 t2 = H2FMA(uh2(P1[2]), s2, w2);
                    const h2 t3 = H2FMA(uh2(P1[3]), s2, w3);
                    const h2 t4 = H2FMA(uh2(P1[4]), s2, w4);
                    h2 mm = h2max(h2max(h2max(t0, t1), h2max(t2, t3)), t4);
                    acc1[oi] = (p == 0) ? mm : h2max(acc1[oi], mm);
                }
            }
        }
    }

    // ---- epilogue: y = acc*s + bias*s in f32 ----
#pragma unroll
    for (int a = 0; a < 4; ++a) {
        float4 o;
        o.x = fmaf((float)acc0[a][0], s, bvs);
        o.y = fmaf((float)acc0[a][1], s, bvs);
        o.z = fmaf((float)acc1[a][0], s, bvs);
        o.w = fmaf((float)acc1[a][1], s, bvs);
        *reinterpret_cast<float4*>(yp + (size_t)(i0 + a) * WW + j0) = o;
    }
}

extern "C" void kernel_launch(void* const* d_in, const int* in_sizes, int n_in,
                              void* d_out, int out_size, void* d_ws, size_t ws_size,
                              hipStream_t stream) {
    (void)d_ws; (void)ws_size; (void)in_sizes; (void)n_in; (void)out_size;
    const float* x    = (const float*)d_in[0];
    const float* w    = (const float*)d_in[1];
    const float* bias = (const float*)d_in[2];
    const float* sign = (const float*)d_in[3];
    float* out = (float*)d_out;

    morpho_kernel<<<4096, 256, 0, stream>>>(x, w, bias, sign, out);
}